// Round 12
// baseline (73.713 us; speedup 1.0000x reference)
//
#include <hip/hip_runtime.h>
#include <stdint.h>

// Round 12: revert to coherent NT stores (r11's sc0/sc1 bypass raced the
// harness's memset-cached lines -> stale readback). Split pass A by concern:
//   A1: flags only (reads 128MB, writes fw 2MB) -- pure-read, 16 pinned
//       float4 loads in flight per thread (2x r10's outstanding bytes).
//   A2: expand fw -> hit/dec (reads 2MB L2-hot, writes 64MB NT) -- pure-write.
//   B : round-10 proven scan (pinned prefetch, LDS transpose, NT proj).
// Order A1->A2->B so A2's drain overlaps B's L3 reads and the next replay's
// A1 follows only B's ~36MB drain.

#define SEGB 128
#define WB   64
#define CHB  16
#define ATILE 64
#define SEG4 256
#define W4   128

#define PIN4(v) asm volatile("" : "+v"((v).x), "+v"((v).y), "+v"((v).z), "+v"((v).w))
#define PIN1(v) asm volatile("" : "+v"(v))

typedef float f32x4 __attribute__((ext_vector_type(4)));

__device__ __forceinline__ void nt_store4(float* addr, float4 v) {
    f32x4 w;
    w.x = v.x; w.y = v.y; w.z = v.z; w.w = v.w;
    __builtin_nontemporal_store(w, (f32x4*)addr);   // nt only: stays coherent
}

__device__ __forceinline__ void sdp_step(float e, float srcv, bool active, bool event,
                                         float& c, float& p, float& prj) {
    const float anchor = fmaxf(srcv, 1.0f);
    const float total  = fmaxf(e + c, 0.0f);
    const float f0     = floorf(total + 0.5f);
    const float L = ceilf(anchor - (24.0f + p));   // reference order
    const float U = floorf(anchor + (24.0f - p));
    // verified identity: clamp(max(f0,1),max(L,1),max(U,lower)) == max3(min(f0,U),L,1)
    const float frames = fmaxf(fmaxf(fminf(f0, U), L), 1.0f);
    const float nc = total - frames;
    prj = active ? frames : anchor;
    const float c1 = active ? nc : c;
    c = event ? nc * 0.25f : c1;                    // *0.25 exact
    const float np  = active ? p + (frames - anchor) : p;
    const float npc = fminf(fmaxf(np * 0.25f, -24.0f), 24.0f);
    p = event ? npc : np;
}

// ---------------- Kernel A1: flags only (pure read) ----------------
__global__ __launch_bounds__(256)
void sdp_flags_kernel(const float* __restrict__ sp_, const float* __restrict__ co_,
                      const float* __restrict__ bd_, const float* __restrict__ pf_,
                      uint32_t* __restrict__ fw, int B, int T) {
    __shared__ uint8_t lb[64][20];            // [row][t4-byte]; 20B stride
    const int ntile = T / ATILE;
    const int g    = blockIdx.x / ntile;
    const int tile = blockIdx.x % ntile;
    const int tid  = threadIdx.x;
    const int w    = tid >> 6;                // wave 0..3
    const int l    = tid & 63;
    const int rsub = l >> 4;                  // 0..3 rows per wave per iter
    const int t4   = l & 15;                  // float4 slot along t
    const long long tb = (long long)tile * ATILE + t4 * 4;

    // issue ALL 16 loads up-front (pinned): 256B/thread in flight
    float4 sA[4], cA[4], bA[4], fA[4];
#pragma unroll
    for (int i = 0; i < 4; ++i) {
        const long long a = (long long)(g * 64 + i * 16 + w * 4 + rsub) * T + tb;
        sA[i] = *(const float4*)(sp_ + a);
        cA[i] = *(const float4*)(co_ + a);
        bA[i] = *(const float4*)(bd_ + a);
        fA[i] = *(const float4*)(pf_ + a);
        PIN4(sA[i]); PIN4(cA[i]); PIN4(bA[i]); PIN4(fA[i]);
    }
#pragma unroll
    for (int i = 0; i < 4; ++i) {
        const int rin = i * 16 + w * 4 + rsub;
        uint32_t byte = 0;
#pragma unroll
        for (int k = 0; k < 4; ++k) {
            const bool active = ((&sA[i].x)[k] > 0.5f) || ((&cA[i].x)[k] > 0.5f);
            const bool event  = active && (((&bA[i].x)[k] >= 0.5f) ||
                                           ((&fA[i].x)[k] > 0.5f));
            if (active) byte |= 1u << (2 * k);
            if (event)  byte |= 1u << (2 * k + 1);
        }
        lb[rin][t4] = (uint8_t)byte;
    }
    __syncthreads();
    // transposed flag-word write: [g][tw][r], 256B-coalesced; block owns 4 tw
    const int r  = tid & 63;
    const int tq = tid >> 6;                  // 0..3 local tw
    const uint32_t wv = *(const uint32_t*)&lb[r][tq * 4];
    fw[(long long)g * (T / 16) * 64 +
       ((long long)tile * (ATILE / 16) + tq) * 64 + r] = wv;
}

// ---------------- Kernel A2: expand fw -> hit/dec (pure write) ----------------
__global__ __launch_bounds__(256)
void sdp_expand_kernel(const uint32_t* __restrict__ fw,
                       float* __restrict__ hit_out, float* __restrict__ dec_out,
                       int B, int T) {
    const int ntile = T / ATILE;
    const int g    = blockIdx.x / ntile;
    const int tile = blockIdx.x % ntile;
    const int tid  = threadIdx.x;
    const int w    = tid >> 6;
    const int l    = tid & 63;
    const int rsub = l >> 4;
    const int t4   = l & 15;
    const int T16  = T / 16;
    const long long tb = (long long)tile * ATILE + t4 * 4;

#pragma unroll
    for (int i = 0; i < 4; ++i) {
        const int rin = i * 16 + w * 4 + rsub;
        const uint32_t wv = fw[(long long)g * T16 * 64 +
                               ((long long)tile * 4 + (t4 >> 2)) * 64 + rin];
        const uint32_t byte = wv >> (8 * (t4 & 3));
        float4 h;
#pragma unroll
        for (int k = 0; k < 4; ++k)
            (&h.x)[k] = ((byte >> (2 * k + 1)) & 1u) ? 1.0f : 0.0f;
        const long long a = (long long)(g * 64 + rin) * T + tb;
        nt_store4(hit_out + a, h);            // 4 rows x 256B runs per wave-instr
        nt_store4(dec_out + a, h);            // dec == hit (DECAY<1 static)
    }
}

// ---------------- Kernel B: coalesced speculative scan (round-10 proven) ----
__global__ __launch_bounds__(64)
void sdp_scan_t_kernel(const float* __restrict__ ex_, const float* __restrict__ src_,
                       const uint32_t* __restrict__ fw,
                       const float* __restrict__ cinit, const float* __restrict__ pinit,
                       float* __restrict__ out, int B, int T, int nseg) {
    __shared__ __align__(16) float exb[2 * 64 * 18];
    __shared__ __align__(16) float srb[2 * 64 * 18];
    __shared__ __align__(16) float pjb[64 * 18];

    const int l  = threadIdx.x;
    const int rg = B / 64;
    const int g  = blockIdx.x % rg;
    const int s  = blockIdx.x / rg;

    const int warm = s ? WB : 0;
    const int t0   = s * SEGB - warm;
    const int nch  = (SEGB + warm) / CHB;     // 8 (s==0) or 12
    const int wch  = warm / CHB;              // 0 or 4

    const int u0 = l >> 2;                    // row-in-group for coop loads
    const int j4 = (l & 3) * 4;               // float offset within 16-step chunk
    const long long g64 = (long long)g * 64;
    const long long fwbase = (long long)g * (T / 16) * 64;
    const long long BT = (long long)B * T;

    float c = s ? 0.0f : cinit[g64 + l];
    float p = s ? 0.0f : pinit[g64 + l];

    float4 rex[4], rsr[4];
    uint32_t rfC, rfN = 0;

    // prologue: load + stage chunk 0, issue chunk 1 (pinned)
    {
        const int tc = t0;
#pragma unroll
        for (int q = 0; q < 4; ++q) {
            const long long a = (g64 + q * 16 + u0) * T + tc + j4;
            rex[q] = *(const float4*)(ex_ + a);
            rsr[q] = *(const float4*)(src_ + a);
        }
        rfC = fw[fwbase + (long long)(tc >> 4) * 64 + l];
#pragma unroll
        for (int q = 0; q < 4; ++q) {
            const int uu = q * 16 + u0;
            *(float4*)&exb[uu * 18 + j4] = rex[q];
            *(float4*)&srb[uu * 18 + j4] = rsr[q];
        }
    }
    if (nch > 1) {
        const int tc = t0 + CHB;
#pragma unroll
        for (int q = 0; q < 4; ++q) {
            const long long a = (g64 + q * 16 + u0) * T + tc + j4;
            rex[q] = *(const float4*)(ex_ + a);
            rsr[q] = *(const float4*)(src_ + a);
            PIN4(rex[q]);
            PIN4(rsr[q]);
        }
        rfN = fw[fwbase + (long long)(tc >> 4) * 64 + l];
        PIN1(rfN);
    }

    int buf = 0;
    for (int ch = 0; ch < nch; ++ch) {
        // compute 16 steps from LDS buf (lane l walks row g*64+l)
        float4 prj[4];
        const int lbase = buf * 1152 + l * 18;
#pragma unroll
        for (int j2 = 0; j2 < 8; ++j2) {
            const float2 e2 = *(const float2*)&exb[lbase + j2 * 2];
            const float2 s2 = *(const float2*)&srb[lbase + j2 * 2];
#pragma unroll
            for (int k = 0; k < 2; ++k) {
                const int j  = j2 * 2 + k;
                const int sh = 8 * (j >> 2) + 2 * (j & 3);
                const bool active = (rfC >> sh) & 1u;
                const bool event  = (rfC >> (sh + 1)) & 1u;
                float pr;
                sdp_step((&e2.x)[k], (&s2.x)[k], active, event, c, p, pr);
                (&prj[j >> 2].x)[j & 3] = pr;
            }
        }

        if (ch >= wch) {
            // stage proj through LDS -> full-line cooperative NT stores
#pragma unroll
            for (int q = 0; q < 4; ++q)
                *(float4*)&pjb[l * 18 + q * 4] = prj[q];
            const int tc = t0 + ch * CHB;
#pragma unroll
            for (int q = 0; q < 4; ++q) {
                const float4 v = *(const float4*)&pjb[(q * 16 + u0) * 18 + j4];
                nt_store4(out + (g64 + q * 16 + u0) * T + tc + j4, v);
            }
        }

        __builtin_amdgcn_sched_barrier(0);

        if (ch + 1 < nch) {
            // stage chunk ch+1 (its loads were issued+pinned one iteration ago)
#pragma unroll
            for (int q = 0; q < 4; ++q) {
                const int uu = q * 16 + u0;
                *(float4*)&exb[(buf ^ 1) * 1152 + uu * 18 + j4] = rex[q];
                *(float4*)&srb[(buf ^ 1) * 1152 + uu * 18 + j4] = rsr[q];
            }
            rfC = rfN;
            if (ch + 2 < nch) {
                const int tc = t0 + (ch + 2) * CHB;
#pragma unroll
                for (int q = 0; q < 4; ++q) {
                    const long long a = (g64 + q * 16 + u0) * T + tc + j4;
                    rex[q] = *(const float4*)(ex_ + a);
                    rsr[q] = *(const float4*)(src_ + a);
                    PIN4(rex[q]);
                    PIN4(rsr[q]);
                }
                rfN = fw[fwbase + (long long)(tc >> 4) * 64 + l];
                PIN1(rfN);
            }
            buf ^= 1;
        }
    }

    if (s == nseg - 1) {
        out[3 * BT + g64 + l]     = c;
        out[3 * BT + B + g64 + l] = p;
    }
}

// ---------------- fallbacks (round-4 proven) ----------------
__global__ __launch_bounds__(64)
void sdp_spec_kernel(const float* __restrict__ ex_, const float* __restrict__ src_,
                     const float* __restrict__ sp_, const float* __restrict__ co_,
                     const float* __restrict__ bd_, const float* __restrict__ pf_,
                     const float* __restrict__ cinit, const float* __restrict__ pinit,
                     float* __restrict__ out, int B, int T, int nseg) {
    const int lane = threadIdx.x;
    const int rgrps = B / 64;
    const int s = blockIdx.x / rgrps;
    const int r = (blockIdx.x % rgrps) * 64 + lane;
    const long long base = (long long)r * T;
    const long long BT = (long long)B * T;
    const int warm = s ? W4 : 0;
    const int t0 = s * SEG4 - warm;
    const int nch = (SEG4 + warm) / 4;
    const int wch = warm / 4;
    const float* pe  = ex_  + base + t0;
    const float* ps  = src_ + base + t0;
    const float* psp = sp_  + base + t0;
    const float* pco = co_  + base + t0;
    const float* pbd = bd_  + base + t0;
    const float* ppf = pf_  + base + t0;
    float* pproj = out + base + t0;
    float* phit  = out + BT + base + t0;
    float* pdec  = out + 2 * BT + base + t0;
    float c = s ? 0.0f : cinit[r];
    float p = s ? 0.0f : pinit[r];
    float4 e4 = *(const float4*)(pe), s4 = *(const float4*)(ps);
    float4 sp4 = *(const float4*)(psp), co4 = *(const float4*)(pco);
    float4 bd4 = *(const float4*)(pbd), pf4 = *(const float4*)(ppf);
    for (int ch = 0; ch < nch; ++ch) {
        float4 ne, ns, nsp, nco, nbd, npf;
        const bool more = (ch + 1 < nch);
        if (more) {
            const int tn = (ch + 1) * 4;
            ne = *(const float4*)(pe + tn);  ns = *(const float4*)(ps + tn);
            nsp = *(const float4*)(psp + tn); nco = *(const float4*)(pco + tn);
            nbd = *(const float4*)(pbd + tn); npf = *(const float4*)(ppf + tn);
        }
        float4 prj, ht;
#pragma unroll
        for (int k = 0; k < 4; ++k) {
            const bool active = ((&sp4.x)[k] > 0.5f) || ((&co4.x)[k] > 0.5f);
            const bool event  = active && (((&bd4.x)[k] >= 0.5f) || ((&pf4.x)[k] > 0.5f));
            float pr;
            sdp_step((&e4.x)[k], (&s4.x)[k], active, event, c, p, pr);
            (&prj.x)[k] = pr;
            (&ht.x)[k]  = event ? 1.0f : 0.0f;
        }
        if (ch >= wch) {
            const int t = ch * 4;
            *(float4*)(pproj + t) = prj;
            *(float4*)(phit  + t) = ht;
            *(float4*)(pdec  + t) = ht;
        }
        if (more) { e4 = ne; s4 = ns; sp4 = nsp; co4 = nco; bd4 = nbd; pf4 = npf; }
    }
    if (s == nseg - 1) {
        out[3 * BT + r]     = c;
        out[3 * BT + B + r] = p;
    }
}

__global__ __launch_bounds__(64)
void sdp_simple_kernel(const float* __restrict__ ex_, const float* __restrict__ src_,
                       const float* __restrict__ sp_, const float* __restrict__ co_,
                       const float* __restrict__ bd_, const float* __restrict__ pf_,
                       const float* __restrict__ cinit, const float* __restrict__ pinit,
                       float* __restrict__ out, int B, int T) {
    const int r = blockIdx.x * 64 + threadIdx.x;
    if (r >= B) return;
    const long long base = (long long)r * T;
    const long long BT = (long long)B * T;
    float c = cinit[r];
    float p = pinit[r];
    for (int t = 0; t < T; ++t) {
        const bool active = (sp_[base + t] > 0.5f) || (co_[base + t] > 0.5f);
        const bool event  = active && ((bd_[base + t] >= 0.5f) || (pf_[base + t] > 0.5f));
        float pr;
        sdp_step(ex_[base + t], src_[base + t], active, event, c, p, pr);
        out[base + t] = pr;
        const float h = event ? 1.0f : 0.0f;
        out[BT + base + t] = h;
        out[2 * BT + base + t] = h;
    }
    out[3 * BT + r]     = c;
    out[3 * BT + B + r] = p;
}

extern "C" void kernel_launch(void* const* d_in, const int* in_sizes, int n_in,
                              void* d_out, int out_size, void* d_ws, size_t ws_size,
                              hipStream_t stream) {
    const float* ex_  = (const float*)d_in[0];
    const float* src_ = (const float*)d_in[1];
    const float* sp_  = (const float*)d_in[2];
    const float* co_  = (const float*)d_in[3];
    const float* bd_  = (const float*)d_in[4];
    const float* pf_  = (const float*)d_in[5];
    const float* ci_  = (const float*)d_in[6];
    const float* pi_  = (const float*)d_in[7];

    const int B = in_sizes[6];
    const int T = in_sizes[0] / B;
    float* out = (float*)d_out;
    const long long BT = (long long)B * T;
    const size_t need_ws = (size_t)B * (size_t)(T / 16) * 4;

    if ((B % 64) == 0 && (T % ATILE) == 0 && (T % SEGB) == 0 &&
        ws_size >= need_ws) {
        uint32_t* fw = (uint32_t*)d_ws;
        const int ablocks = (B / 64) * (T / ATILE);
        sdp_flags_kernel<<<dim3(ablocks), dim3(256), 0, stream>>>(
            sp_, co_, bd_, pf_, fw, B, T);
        sdp_expand_kernel<<<dim3(ablocks), dim3(256), 0, stream>>>(
            fw, out + BT, out + 2 * BT, B, T);
        const int nseg = T / SEGB;
        const int bblocks = nseg * (B / 64);
        sdp_scan_t_kernel<<<dim3(bblocks), dim3(64), 0, stream>>>(
            ex_, src_, fw, ci_, pi_, out, B, T, nseg);
    } else if ((B % 64) == 0 && (T % SEG4) == 0 && T >= SEG4 + W4) {
        const int nseg = T / SEG4;
        sdp_spec_kernel<<<dim3((B / 64) * nseg), dim3(64), 0, stream>>>(
            ex_, src_, sp_, co_, bd_, pf_, ci_, pi_, out, B, T, nseg);
    } else {
        sdp_simple_kernel<<<dim3((B + 63) / 64), dim3(64), 0, stream>>>(
            ex_, src_, sp_, co_, bd_, pf_, ci_, pi_, out, B, T);
    }
}

// Round 13
// 73.201 us; speedup vs baseline: 1.0070x; 1.0070x over previous
//
#include <hip/hip_runtime.h>
#include <stdint.h>

// Round 13: fold A2 (hit/dec expansion) into B's store phase.
// r12 showed the total (~73us) is invariant under kernel restructuring ->
// system is near its mixed-stream BW equilibrium (~4.5 TB/s effective on
// ~330MB/replay). Last redundancies: A2's separate launch + second fw read.
// B's block (g,s) owns exactly the (rows,steps) tile of A2's writes and
// already holds the fw words in registers -> expand via __shfl(rfC,row) and
// NT-store hit/dec alongside proj in one write phase.
//   A1: flags only (reads 128MB, writes fw 2MB), 16 pinned loads in flight.
//   B : scan + ALL output stores (proj/hit/dec, ~100MB NT).

#define SEGB 128
#define WB   64
#define CHB  16
#define ATILE 64
#define SEG4 256
#define W4   128

#define PIN4(v) asm volatile("" : "+v"((v).x), "+v"((v).y), "+v"((v).z), "+v"((v).w))
#define PIN1(v) asm volatile("" : "+v"(v))

typedef float f32x4 __attribute__((ext_vector_type(4)));

__device__ __forceinline__ void nt_store4(float* addr, float4 v) {
    f32x4 w;
    w.x = v.x; w.y = v.y; w.z = v.z; w.w = v.w;
    __builtin_nontemporal_store(w, (f32x4*)addr);   // nt only: stays coherent
}

__device__ __forceinline__ void sdp_step(float e, float srcv, bool active, bool event,
                                         float& c, float& p, float& prj) {
    const float anchor = fmaxf(srcv, 1.0f);
    const float total  = fmaxf(e + c, 0.0f);
    const float f0     = floorf(total + 0.5f);
    const float L = ceilf(anchor - (24.0f + p));   // reference order
    const float U = floorf(anchor + (24.0f - p));
    // verified identity: clamp(max(f0,1),max(L,1),max(U,lower)) == max3(min(f0,U),L,1)
    const float frames = fmaxf(fmaxf(fminf(f0, U), L), 1.0f);
    const float nc = total - frames;
    prj = active ? frames : anchor;
    const float c1 = active ? nc : c;
    c = event ? nc * 0.25f : c1;                    // *0.25 exact
    const float np  = active ? p + (frames - anchor) : p;
    const float npc = fminf(fmaxf(np * 0.25f, -24.0f), 24.0f);
    p = event ? npc : np;
}

// ---------------- Kernel A1: flags only (pure read) ----------------
__global__ __launch_bounds__(256)
void sdp_flags_kernel(const float* __restrict__ sp_, const float* __restrict__ co_,
                      const float* __restrict__ bd_, const float* __restrict__ pf_,
                      uint32_t* __restrict__ fw, int B, int T) {
    __shared__ uint8_t lb[64][20];            // [row][t4-byte]; 20B stride
    const int ntile = T / ATILE;
    const int g    = blockIdx.x / ntile;
    const int tile = blockIdx.x % ntile;
    const int tid  = threadIdx.x;
    const int w    = tid >> 6;                // wave 0..3
    const int l    = tid & 63;
    const int rsub = l >> 4;                  // 0..3 rows per wave per iter
    const int t4   = l & 15;                  // float4 slot along t
    const long long tb = (long long)tile * ATILE + t4 * 4;

    // issue ALL 16 loads up-front (pinned): 256B/thread in flight
    float4 sA[4], cA[4], bA[4], fA[4];
#pragma unroll
    for (int i = 0; i < 4; ++i) {
        const long long a = (long long)(g * 64 + i * 16 + w * 4 + rsub) * T + tb;
        sA[i] = *(const float4*)(sp_ + a);
        cA[i] = *(const float4*)(co_ + a);
        bA[i] = *(const float4*)(bd_ + a);
        fA[i] = *(const float4*)(pf_ + a);
        PIN4(sA[i]); PIN4(cA[i]); PIN4(bA[i]); PIN4(fA[i]);
    }
#pragma unroll
    for (int i = 0; i < 4; ++i) {
        const int rin = i * 16 + w * 4 + rsub;
        uint32_t byte = 0;
#pragma unroll
        for (int k = 0; k < 4; ++k) {
            const bool active = ((&sA[i].x)[k] > 0.5f) || ((&cA[i].x)[k] > 0.5f);
            const bool event  = active && (((&bA[i].x)[k] >= 0.5f) ||
                                           ((&fA[i].x)[k] > 0.5f));
            if (active) byte |= 1u << (2 * k);
            if (event)  byte |= 1u << (2 * k + 1);
        }
        lb[rin][t4] = (uint8_t)byte;
    }
    __syncthreads();
    // transposed flag-word write: [g][tw][r], 256B-coalesced; block owns 4 tw
    const int r  = tid & 63;
    const int tq = tid >> 6;                  // 0..3 local tw
    const uint32_t wv = *(const uint32_t*)&lb[r][tq * 4];
    fw[(long long)g * (T / 16) * 64 +
       ((long long)tile * (ATILE / 16) + tq) * 64 + r] = wv;
}

// ------- Kernel B: scan + proj/hit/dec stores (A2 folded in) -------
__global__ __launch_bounds__(64)
void sdp_scan_t_kernel(const float* __restrict__ ex_, const float* __restrict__ src_,
                       const uint32_t* __restrict__ fw,
                       const float* __restrict__ cinit, const float* __restrict__ pinit,
                       float* __restrict__ out, int B, int T, int nseg) {
    __shared__ __align__(16) float exb[2 * 64 * 18];
    __shared__ __align__(16) float srb[2 * 64 * 18];
    __shared__ __align__(16) float pjb[64 * 18];

    const int l  = threadIdx.x;
    const int rg = B / 64;
    const int g  = blockIdx.x % rg;
    const int s  = blockIdx.x / rg;

    const int warm = s ? WB : 0;
    const int t0   = s * SEGB - warm;
    const int nch  = (SEGB + warm) / CHB;     // 8 (s==0) or 12
    const int wch  = warm / CHB;              // 0 or 4

    const int u0 = l >> 2;                    // row-in-group for coop loads
    const int j4 = (l & 3) * 4;               // float offset within 16-step chunk
    const int shb = 8 * (l & 3);              // event-bit base after shuffle
    const long long g64 = (long long)g * 64;
    const long long fwbase = (long long)g * (T / 16) * 64;
    const long long BT = (long long)B * T;
    float* hit_out = out + BT;
    float* dec_out = out + 2 * BT;

    float c = s ? 0.0f : cinit[g64 + l];
    float p = s ? 0.0f : pinit[g64 + l];

    float4 rex[4], rsr[4];
    uint32_t rfC, rfN = 0;

    // prologue: load + stage chunk 0, issue chunk 1 (pinned)
    {
        const int tc = t0;
#pragma unroll
        for (int q = 0; q < 4; ++q) {
            const long long a = (g64 + q * 16 + u0) * T + tc + j4;
            rex[q] = *(const float4*)(ex_ + a);
            rsr[q] = *(const float4*)(src_ + a);
        }
        rfC = fw[fwbase + (long long)(tc >> 4) * 64 + l];
#pragma unroll
        for (int q = 0; q < 4; ++q) {
            const int uu = q * 16 + u0;
            *(float4*)&exb[uu * 18 + j4] = rex[q];
            *(float4*)&srb[uu * 18 + j4] = rsr[q];
        }
    }
    if (nch > 1) {
        const int tc = t0 + CHB;
#pragma unroll
        for (int q = 0; q < 4; ++q) {
            const long long a = (g64 + q * 16 + u0) * T + tc + j4;
            rex[q] = *(const float4*)(ex_ + a);
            rsr[q] = *(const float4*)(src_ + a);
            PIN4(rex[q]);
            PIN4(rsr[q]);
        }
        rfN = fw[fwbase + (long long)(tc >> 4) * 64 + l];
        PIN1(rfN);
    }

    int buf = 0;
    for (int ch = 0; ch < nch; ++ch) {
        // compute 16 steps from LDS buf (lane l walks row g*64+l)
        float4 prj[4];
        const int lbase = buf * 1152 + l * 18;
#pragma unroll
        for (int j2 = 0; j2 < 8; ++j2) {
            const float2 e2 = *(const float2*)&exb[lbase + j2 * 2];
            const float2 s2 = *(const float2*)&srb[lbase + j2 * 2];
#pragma unroll
            for (int k = 0; k < 2; ++k) {
                const int j  = j2 * 2 + k;
                const int sh = 8 * (j >> 2) + 2 * (j & 3);
                const bool active = (rfC >> sh) & 1u;
                const bool event  = (rfC >> (sh + 1)) & 1u;
                float pr;
                sdp_step((&e2.x)[k], (&s2.x)[k], active, event, c, p, pr);
                (&prj[j >> 2].x)[j & 3] = pr;
            }
        }

        if (ch >= wch) {
            // stage proj through LDS; store proj + hit + dec as full-line runs
#pragma unroll
            for (int q = 0; q < 4; ++q)
                *(float4*)&pjb[l * 18 + q * 4] = prj[q];
            const int tc = t0 + ch * CHB;
#pragma unroll
            for (int q = 0; q < 4; ++q) {
                const int rr = q * 16 + u0;
                const long long a = (g64 + rr) * T + tc + j4;
                const float4 v = *(const float4*)&pjb[rr * 18 + j4];
                nt_store4(out + a, v);
                // hit/dec: expand row rr's event bits (steps j4..j4+3)
                const uint32_t wv = __shfl(rfC, rr);
                float4 h;
#pragma unroll
                for (int k = 0; k < 4; ++k)
                    (&h.x)[k] = ((wv >> (shb + 2 * k + 1)) & 1u) ? 1.0f : 0.0f;
                nt_store4(hit_out + a, h);
                nt_store4(dec_out + a, h);    // dec == hit (DECAY<1 static)
            }
        }

        __builtin_amdgcn_sched_barrier(0);

        if (ch + 1 < nch) {
            // stage chunk ch+1 (its loads were issued+pinned one iteration ago)
#pragma unroll
            for (int q = 0; q < 4; ++q) {
                const int uu = q * 16 + u0;
                *(float4*)&exb[(buf ^ 1) * 1152 + uu * 18 + j4] = rex[q];
                *(float4*)&srb[(buf ^ 1) * 1152 + uu * 18 + j4] = rsr[q];
            }
            rfC = rfN;
            if (ch + 2 < nch) {
                const int tc = t0 + (ch + 2) * CHB;
#pragma unroll
                for (int q = 0; q < 4; ++q) {
                    const long long a = (g64 + q * 16 + u0) * T + tc + j4;
                    rex[q] = *(const float4*)(ex_ + a);
                    rsr[q] = *(const float4*)(src_ + a);
                    PIN4(rex[q]);
                    PIN4(rsr[q]);
                }
                rfN = fw[fwbase + (long long)(tc >> 4) * 64 + l];
                PIN1(rfN);
            }
            buf ^= 1;
        }
    }

    if (s == nseg - 1) {
        out[3 * BT + g64 + l]     = c;
        out[3 * BT + B + g64 + l] = p;
    }
}

// ---------------- fallbacks (round-4 proven) ----------------
__global__ __launch_bounds__(64)
void sdp_spec_kernel(const float* __restrict__ ex_, const float* __restrict__ src_,
                     const float* __restrict__ sp_, const float* __restrict__ co_,
                     const float* __restrict__ bd_, const float* __restrict__ pf_,
                     const float* __restrict__ cinit, const float* __restrict__ pinit,
                     float* __restrict__ out, int B, int T, int nseg) {
    const int lane = threadIdx.x;
    const int rgrps = B / 64;
    const int s = blockIdx.x / rgrps;
    const int r = (blockIdx.x % rgrps) * 64 + lane;
    const long long base = (long long)r * T;
    const long long BT = (long long)B * T;
    const int warm = s ? W4 : 0;
    const int t0 = s * SEG4 - warm;
    const int nch = (SEG4 + warm) / 4;
    const int wch = warm / 4;
    const float* pe  = ex_  + base + t0;
    const float* ps  = src_ + base + t0;
    const float* psp = sp_  + base + t0;
    const float* pco = co_  + base + t0;
    const float* pbd = bd_  + base + t0;
    const float* ppf = pf_  + base + t0;
    float* pproj = out + base + t0;
    float* phit  = out + BT + base + t0;
    float* pdec  = out + 2 * BT + base + t0;
    float c = s ? 0.0f : cinit[r];
    float p = s ? 0.0f : pinit[r];
    float4 e4 = *(const float4*)(pe), s4 = *(const float4*)(ps);
    float4 sp4 = *(const float4*)(psp), co4 = *(const float4*)(pco);
    float4 bd4 = *(const float4*)(pbd), pf4 = *(const float4*)(ppf);
    for (int ch = 0; ch < nch; ++ch) {
        float4 ne, ns, nsp, nco, nbd, npf;
        const bool more = (ch + 1 < nch);
        if (more) {
            const int tn = (ch + 1) * 4;
            ne = *(const float4*)(pe + tn);  ns = *(const float4*)(ps + tn);
            nsp = *(const float4*)(psp + tn); nco = *(const float4*)(pco + tn);
            nbd = *(const float4*)(pbd + tn); npf = *(const float4*)(ppf + tn);
        }
        float4 prj, ht;
#pragma unroll
        for (int k = 0; k < 4; ++k) {
            const bool active = ((&sp4.x)[k] > 0.5f) || ((&co4.x)[k] > 0.5f);
            const bool event  = active && (((&bd4.x)[k] >= 0.5f) || ((&pf4.x)[k] > 0.5f));
            float pr;
            sdp_step((&e4.x)[k], (&s4.x)[k], active, event, c, p, pr);
            (&prj.x)[k] = pr;
            (&ht.x)[k]  = event ? 1.0f : 0.0f;
        }
        if (ch >= wch) {
            const int t = ch * 4;
            *(float4*)(pproj + t) = prj;
            *(float4*)(phit  + t) = ht;
            *(float4*)(pdec  + t) = ht;
        }
        if (more) { e4 = ne; s4 = ns; sp4 = nsp; co4 = nco; bd4 = nbd; pf4 = npf; }
    }
    if (s == nseg - 1) {
        out[3 * BT + r]     = c;
        out[3 * BT + B + r] = p;
    }
}

__global__ __launch_bounds__(64)
void sdp_simple_kernel(const float* __restrict__ ex_, const float* __restrict__ src_,
                       const float* __restrict__ sp_, const float* __restrict__ co_,
                       const float* __restrict__ bd_, const float* __restrict__ pf_,
                       const float* __restrict__ cinit, const float* __restrict__ pinit,
                       float* __restrict__ out, int B, int T) {
    const int r = blockIdx.x * 64 + threadIdx.x;
    if (r >= B) return;
    const long long base = (long long)r * T;
    const long long BT = (long long)B * T;
    float c = cinit[r];
    float p = pinit[r];
    for (int t = 0; t < T; ++t) {
        const bool active = (sp_[base + t] > 0.5f) || (co_[base + t] > 0.5f);
        const bool event  = active && ((bd_[base + t] >= 0.5f) || (pf_[base + t] > 0.5f));
        float pr;
        sdp_step(ex_[base + t], src_[base + t], active, event, c, p, pr);
        out[base + t] = pr;
        const float h = event ? 1.0f : 0.0f;
        out[BT + base + t] = h;
        out[2 * BT + base + t] = h;
    }
    out[3 * BT + r]     = c;
    out[3 * BT + B + r] = p;
}

extern "C" void kernel_launch(void* const* d_in, const int* in_sizes, int n_in,
                              void* d_out, int out_size, void* d_ws, size_t ws_size,
                              hipStream_t stream) {
    const float* ex_  = (const float*)d_in[0];
    const float* src_ = (const float*)d_in[1];
    const float* sp_  = (const float*)d_in[2];
    const float* co_  = (const float*)d_in[3];
    const float* bd_  = (const float*)d_in[4];
    const float* pf_  = (const float*)d_in[5];
    const float* ci_  = (const float*)d_in[6];
    const float* pi_  = (const float*)d_in[7];

    const int B = in_sizes[6];
    const int T = in_sizes[0] / B;
    float* out = (float*)d_out;
    const size_t need_ws = (size_t)B * (size_t)(T / 16) * 4;

    if ((B % 64) == 0 && (T % ATILE) == 0 && (T % SEGB) == 0 &&
        ws_size >= need_ws) {
        uint32_t* fw = (uint32_t*)d_ws;
        const int ablocks = (B / 64) * (T / ATILE);
        sdp_flags_kernel<<<dim3(ablocks), dim3(256), 0, stream>>>(
            sp_, co_, bd_, pf_, fw, B, T);
        const int nseg = T / SEGB;
        const int bblocks = nseg * (B / 64);
        sdp_scan_t_kernel<<<dim3(bblocks), dim3(64), 0, stream>>>(
            ex_, src_, fw, ci_, pi_, out, B, T, nseg);
    } else if ((B % 64) == 0 && (T % SEG4) == 0 && T >= SEG4 + W4) {
        const int nseg = T / SEG4;
        sdp_spec_kernel<<<dim3((B / 64) * nseg), dim3(64), 0, stream>>>(
            ex_, src_, sp_, co_, bd_, pf_, ci_, pi_, out, B, T, nseg);
    } else {
        sdp_simple_kernel<<<dim3((B + 63) / 64), dim3(64), 0, stream>>>(
            ex_, src_, sp_, co_, bd_, pf_, ci_, pi_, out, B, T);
    }
}